// Round 1
// baseline (21149.046 us; speedup 1.0000x reference)
//
#include <hip/hip_runtime.h>
#include <hip/hip_cooperative_groups.h>
#include <math.h>

namespace cg = cooperative_groups;

#define BB 64
#define TT 512
#define FF 512
#define HH 1024
// 4H = 4096

typedef _Float16 half8 __attribute__((ext_vector_type(8)));
typedef float f32x4 __attribute__((ext_vector_type(4)));

__device__ __forceinline__ float sigm(float x) {
    return 1.0f / (1.0f + __expf(-x));
}
__device__ __forceinline__ float tanh_fast(float x) {
    x = fminf(fmaxf(x, -30.0f), 30.0f);
    float e = __expf(2.0f * x);
    return (e - 1.0f) / (e + 1.0f);
}

// One persistent cooperative kernel. 256 wgs (1/CU) x 256 threads (4 waves).
// wg owns h-cols [4*wg, 4*wg+4) -> 16 gemm cols (4 gates x 4), W slices in LDS f16.
// h double-buffer lives inside d_out (2 * 64*1024 f16 == out_size*4 bytes exactly).
__global__ __launch_bounds__(256, 1) void lstm_fused(
    const float* __restrict__ x,      // [B,T,F]
    const float* __restrict__ w_xh,   // [F,4H]
    const float* __restrict__ w_hh,   // [H,4H]
    const float* __restrict__ bias,   // [4H]
    const float* __restrict__ scale,  // [T,H]
    const float* __restrict__ offs,   // [T,H]
    const float* __restrict__ pmean,  // [T,H]
    const float* __restrict__ pvar,   // [T,H]
    float* __restrict__ out)          // [B,H] fp32; scratch h-buffers during run
{
    constexpr int KPADH = HH + 8;   // f16 row stride 2064 B -> bank offset 4/row (2-way max, free)
    constexpr int KPADF = FF + 8;   // 1040 B -> same
    __shared__ __align__(16) _Float16 whh_l[16 * KPADH]; // 33.0 KB
    __shared__ __align__(16) _Float16 wxh_l[16 * KPADF]; // 16.6 KB
    __shared__ float bias_l[16];
    __shared__ float gbuf[64 * 17];                      // 4.3 KB, padded

    const int wg  = blockIdx.x;    // 0..255
    const int tid = threadIdx.x;   // 0..255

    // ---- one-time setup: gather 16 columns (gate*H + 4*wg + d) of W_HH / W_XH into LDS (f16)
    for (int idx = tid; idx < 16 * HH; idx += 256) {
        int n = idx & 15, k = idx >> 4;
        int col = (n >> 2) * HH + wg * 4 + (n & 3);
        whh_l[n * KPADH + k] = (_Float16)w_hh[k * (4 * HH) + col];
    }
    for (int idx = tid; idx < 16 * FF; idx += 256) {
        int n = idx & 15, k = idx >> 4;
        int col = (n >> 2) * HH + wg * 4 + (n & 3);
        wxh_l[n * KPADF + k] = (_Float16)w_xh[k * (4 * HH) + col];
    }
    if (tid < 16) bias_l[tid] = bias[(tid >> 2) * HH + wg * 4 + (tid & 3)];

    _Float16* hbuf = (_Float16*)out;       // buffer0 = [0,64K), buffer1 = [64K,128K) halves
    const int m = tid >> 2, d = tid & 3;   // epilogue: one thread per (batch row, owned h-col)
    const int mycol = wg * 4 + d;
    hbuf[m * HH + mycol] = (_Float16)0.0f; // zero h buffer 0 (collectively complete)

    const int lane = tid & 63, wid = tid >> 6;
    const int q = lane >> 4, r = lane & 15;
    const int mrow = wid * 16 + r;         // A-frag row: lane&15 ; k = (lane>>4)*8 + j

    cg::grid_group grid = cg::this_grid();
    __syncthreads();
    grid.sync();   // h0 zeroed + LDS ready everywhere

    float c_reg = 0.0f, h_out = 0.0f;
    int cur = 0;

    for (int t = 0; t < TT; ++t) {
        f32x4 acc = {0.0f, 0.0f, 0.0f, 0.0f};

        // GEMM1: x_t @ Wxh_slice  (K = 512), fp32 global -> f16 frags on the fly
        const float* xrow = x + ((size_t)mrow * TT + (size_t)t) * FF;
        #pragma unroll 4
        for (int kk = 0; kk < FF / 32; ++kk) {
            int kb = kk * 32 + q * 8;
            float4 x0 = *(const float4*)(xrow + kb);
            float4 x1 = *(const float4*)(xrow + kb + 4);
            half8 a;
            a[0] = (_Float16)x0.x; a[1] = (_Float16)x0.y;
            a[2] = (_Float16)x0.z; a[3] = (_Float16)x0.w;
            a[4] = (_Float16)x1.x; a[5] = (_Float16)x1.y;
            a[6] = (_Float16)x1.z; a[7] = (_Float16)x1.w;
            half8 b = *(const half8*)&wxh_l[r * KPADF + kb];  // B: col = lane&15, k = q*8+j
            acc = __builtin_amdgcn_mfma_f32_16x16x32_f16(a, b, acc, 0, 0, 0);
        }

        // GEMM2: h_{t-1} @ Whh_slice  (K = 1024), h is f16 in global
        const _Float16* hrow = hbuf + cur * (BB * HH) + mrow * HH;
        #pragma unroll 4
        for (int kk = 0; kk < HH / 32; ++kk) {
            int kb = kk * 32 + q * 8;
            half8 a = *(const half8*)(hrow + kb);
            half8 b = *(const half8*)&whh_l[r * KPADH + kb];
            acc = __builtin_amdgcn_mfma_f32_16x16x32_f16(a, b, acc, 0, 0, 0);
        }

        // C/D layout: col = lane&15 (=r), row = (lane>>4)*4 + reg  (+16*wid)
        #pragma unroll
        for (int reg = 0; reg < 4; ++reg)
            gbuf[(wid * 16 + q * 4 + reg) * 17 + r] = acc[reg];
        __syncthreads();

        // cell update: thread owns (m, d); gates at cols {d, 4+d, 8+d, 12+d} = {f,i,o,gbar}
        float f_ = gbuf[m * 17 + 0  + d] + bias_l[0  + d];
        float i_ = gbuf[m * 17 + 4  + d] + bias_l[4  + d];
        float o_ = gbuf[m * 17 + 8  + d] + bias_l[8  + d];
        float g_ = gbuf[m * 17 + 12 + d] + bias_l[12 + d];
        float mu  = pmean[t * HH + mycol];
        float iss = scale[t * HH + mycol] * rsqrtf(pvar[t * HH + mycol] + 1e-5f);
        float of  = offs [t * HH + mycol];
        c_reg = sigm(f_ + 1.0f) * c_reg + sigm(i_) * tanh_fast(g_);
        float cn = (c_reg - mu) * iss + of;
        h_out = sigm(o_) * tanh_fast(cn);
        hbuf[(cur ^ 1) * (BB * HH) + m * HH + mycol] = (_Float16)h_out;

        grid.sync();   // h_next complete + visible device-wide; gbuf reads done
        cur ^= 1;
    }

    // after final grid.sync nobody reads hbuf again -> safe to overwrite with fp32 output
    out[m * HH + mycol] = h_out;
}

extern "C" void kernel_launch(void* const* d_in, const int* in_sizes, int n_in,
                              void* d_out, int out_size, void* d_ws, size_t ws_size,
                              hipStream_t stream) {
    const float* x     = (const float*)d_in[0];
    const float* w_xh  = (const float*)d_in[1];
    const float* w_hh  = (const float*)d_in[2];
    const float* bias  = (const float*)d_in[3];
    const float* scale = (const float*)d_in[4];
    const float* offs  = (const float*)d_in[5];
    const float* pmean = (const float*)d_in[6];
    const float* pvar  = (const float*)d_in[7];
    float* out = (float*)d_out;
    void* args[] = {&x, &w_xh, &w_hh, &bias, &scale, &offs, &pmean, &pvar, &out};
    hipLaunchCooperativeKernel((const void*)lstm_fused, dim3(256), dim3(256),
                               args, 0, stream);
}

// Round 2
// 13720.708 us; speedup vs baseline: 1.5414x; 1.5414x over previous
//
#include <hip/hip_runtime.h>
#include <hip/hip_cooperative_groups.h>
#include <math.h>

namespace cg = cooperative_groups;

#define BB 64
#define TT 512
#define FF 512
#define HH 1024
#define NG 4096  // 4H

typedef _Float16 half8 __attribute__((ext_vector_type(8)));
typedef _Float16 half4 __attribute__((ext_vector_type(4)));
typedef float f32x4 __attribute__((ext_vector_type(4)));

__device__ __forceinline__ float sigm(float x) { return 1.0f / (1.0f + __expf(-x)); }
__device__ __forceinline__ float tanh_fast(float x) {
    x = fminf(fmaxf(x, -30.0f), 30.0f);
    float e = __expf(2.0f * x);
    return (e - 1.0f) / (e + 1.0f);
}

// ---------------------------------------------------------------------------
// Kernel 1: xp[t][wg][n_loc][b] (f16) = x @ W_XH   (bias folded in recurrence)
// n_loc in wg's order: global col = (n_loc>>2)*HH + wg*4 + (n_loc&3)
// grid (NG/64, TT/4) x 256 threads. K staged to LDS in 2 chunks of 256.
// ---------------------------------------------------------------------------
__global__ __launch_bounds__(256) void xproj(const float* __restrict__ x,
                                             const float* __restrict__ w_xh,
                                             _Float16* __restrict__ xp)
{
    constexpr int KP = 264;           // 256 + 8 f16 pad; stride 528 B (16-B aligned, granule-balanced)
    __shared__ __align__(16) _Float16 bl[64 * KP];  // 33.8 KB
    const int nbase = blockIdx.x * 64;
    const int t0 = blockIdx.y * 4;
    const int tid = threadIdx.x;
    const int lane = tid & 63, wid = tid >> 6;
    const int q = lane >> 4, r = lane & 15;
    const int brow = wid * 16 + r;    // batch row for A-frags

    f32x4 acc[4][4] = {};             // [tt][nf]
    for (int ks = 0; ks < 2; ++ks) {
        const int k0 = ks * 256;
        __syncthreads();
        // stage B chunk: 64 cols x 256 k
        for (int i = tid; i < 4096; i += 256) {
            int k = i >> 4, n4 = (i & 15) * 4;
            float4 v = *(const float4*)(w_xh + (size_t)(k0 + k) * NG + nbase + n4);
            bl[(n4 + 0) * KP + k] = (_Float16)v.x;
            bl[(n4 + 1) * KP + k] = (_Float16)v.y;
            bl[(n4 + 2) * KP + k] = (_Float16)v.z;
            bl[(n4 + 3) * KP + k] = (_Float16)v.w;
        }
        __syncthreads();
        for (int kk = 0; kk < 8; ++kk) {
            int kb = kk * 32 + q * 8;
            half8 a[4];
            #pragma unroll
            for (int tt = 0; tt < 4; ++tt) {
                const float* xr = x + ((size_t)brow * TT + t0 + tt) * FF + k0 + kb;
                float4 x0 = *(const float4*)xr;
                float4 x1 = *(const float4*)(xr + 4);
                a[tt][0] = (_Float16)x0.x; a[tt][1] = (_Float16)x0.y;
                a[tt][2] = (_Float16)x0.z; a[tt][3] = (_Float16)x0.w;
                a[tt][4] = (_Float16)x1.x; a[tt][5] = (_Float16)x1.y;
                a[tt][6] = (_Float16)x1.z; a[tt][7] = (_Float16)x1.w;
            }
            #pragma unroll
            for (int nf = 0; nf < 4; ++nf) {
                half8 b = *(const half8*)&bl[(nf * 16 + r) * KP + kb];
                #pragma unroll
                for (int tt = 0; tt < 4; ++tt)
                    acc[tt][nf] = __builtin_amdgcn_mfma_f32_16x16x32_f16(a[tt], b, acc[tt][nf], 0, 0, 0);
            }
        }
    }
    // epilogue: C layout col=lane&15 (=r -> n), row=q*4+reg (-> b), 4 consecutive b per lane
    #pragma unroll
    for (int nf = 0; nf < 4; ++nf) {
        int n = nbase + nf * 16 + r;
        int g = n >> 10, wgt = (n & 1023) >> 2, dd = n & 3;
        int nloc = g * 4 + dd;
        #pragma unroll
        for (int tt = 0; tt < 4; ++tt) {
            half4 v;
            v[0] = (_Float16)acc[tt][nf][0]; v[1] = (_Float16)acc[tt][nf][1];
            v[2] = (_Float16)acc[tt][nf][2]; v[3] = (_Float16)acc[tt][nf][3];
            *(half4*)(xp + ((((size_t)(t0 + tt)) * 256 + wgt) * 16 + nloc) * 64 + wid * 16 + q * 4) = v;
        }
    }
}

// ---------------------------------------------------------------------------
// Fast grid barrier: monotonic counter in d_ws. One agent-scope RMW + spin by
// thread 0. __threadfence (agent rel/acq) flushes/invalidates L2 for cross-XCD
// h visibility — same HW mechanism cg::grid.sync uses, without its overhead.
// ---------------------------------------------------------------------------
__device__ __forceinline__ void fastbar(int* bar, int target, int tid) {
    __syncthreads();                              // all wg stores drained to L2
    if (tid == 0) {
        __threadfence();                          // release: wbl2 to LLC
        __hip_atomic_fetch_add(bar, 1, __ATOMIC_RELAXED, __HIP_MEMORY_SCOPE_AGENT);
        while (__hip_atomic_load(bar, __ATOMIC_RELAXED, __HIP_MEMORY_SCOPE_AGENT) < target) {}
        __threadfence();                          // acquire: inv L1/L2
    }
    __syncthreads();
}

// ---------------------------------------------------------------------------
// Kernel 2: persistent recurrence. 256 wgs (1/CU) x 256 threads.
// MODE 0: xp precomputed in ws, fast barrier.   (primary)
// MODE 1: fused x-GEMM, fast barrier.           (ws too small for xp)
// MODE 2: fused x-GEMM, cg::grid.sync.          (ws < 256 B safety net)
// h double-buffer lives in d_out (2 * 64*1024 f16 == out_size*4 bytes).
// ---------------------------------------------------------------------------
template<int MODE>
__global__ __launch_bounds__(256, 1) void lstm_rec(
    const float* __restrict__ x, const float* __restrict__ w_xh,
    const float* __restrict__ w_hh, const float* __restrict__ bias,
    const float* __restrict__ scale, const float* __restrict__ offs,
    const float* __restrict__ pmean, const float* __restrict__ pvar,
    const _Float16* __restrict__ xp, int* bar, float* __restrict__ out)
{
    constexpr int KPH = HH + 8;   // 1032; row stride 2064 B = 16*129 (aligned, balanced)
    constexpr int KPF = FF + 8;   // 520;  row stride 1040 B = 16*65
    extern __shared__ char smem[];
    _Float16* whh_l  = (_Float16*)smem;                        // 33024 B
    float*    bias_l = (float*)(smem + 33024);                 // 64 B
    float*    gbuf   = (float*)(smem + 33024 + 64);            // 64*17*4 = 4352 B
    _Float16* wxh_l  = (_Float16*)(smem + 33024 + 64 + 4352);  // 16640 B (MODE>=1 only)

    const int wg  = blockIdx.x;
    const int tid = threadIdx.x;

    // one-time: gather the wg's 16 W_HH columns into LDS (f16)
    for (int idx = tid; idx < 16 * HH; idx += 256) {
        int n = idx & 15, k = idx >> 4;
        int col = (n >> 2) * HH + wg * 4 + (n & 3);
        whh_l[n * KPH + k] = (_Float16)w_hh[k * NG + col];
    }
    if constexpr (MODE >= 1) {
        for (int idx = tid; idx < 16 * FF; idx += 256) {
            int n = idx & 15, k = idx >> 4;
            int col = (n >> 2) * HH + wg * 4 + (n & 3);
            wxh_l[n * KPF + k] = (_Float16)w_xh[k * NG + col];
        }
    }
    if (tid < 16) bias_l[tid] = bias[(tid >> 2) * HH + wg * 4 + (tid & 3)];

    _Float16* hbuf = (_Float16*)out;      // buf0=[0,64K) buf1=[64K,128K) halves
    const int m = tid >> 2, d = tid & 3;  // epilogue ownership: (batch m, col d)
    const int mycol = wg * 4 + d;
    hbuf[m * HH + mycol] = (_Float16)0.0f;

    const int lane = tid & 63, wid = tid >> 6;
    const int q = lane >> 4, r = lane & 15;
    const int mrow = wid * 16 + r;        // A-frag row (batch)

    cg::grid_group grid = cg::this_grid();

    // prefetch step-0 params (xp + BN) so their latency hides under the barrier
    half4 xpv;
    float bnmu, bniss, bnoff;
    if constexpr (MODE == 0)
        xpv = *(const half4*)(xp + (((size_t)0 * 256 + wg) * 16 + r) * 64 + wid * 16 + q * 4);
    bnmu  = pmean[0 * HH + mycol];
    bniss = scale[0 * HH + mycol] * rsqrtf(pvar[0 * HH + mycol] + 1e-5f);
    bnoff = offs [0 * HH + mycol];

    int nbar = 1;
    if constexpr (MODE == 2) { __syncthreads(); grid.sync(); }
    else fastbar(bar, 256 * (nbar++), tid);

    float c_reg = 0.0f, h_out = 0.0f;
    int cur = 0;

    for (int t = 0; t < TT; ++t) {
        f32x4 acc;
        if constexpr (MODE == 0) {
            acc[0] = (float)xpv[0]; acc[1] = (float)xpv[1];
            acc[2] = (float)xpv[2]; acc[3] = (float)xpv[3];
        } else {
            acc = (f32x4){0.0f, 0.0f, 0.0f, 0.0f};
            // fused GEMM1: x_t @ Wxh_slice (K=512), fp32 -> f16 on the fly
            const float* xrow = x + ((size_t)mrow * TT + (size_t)t) * FF;
            #pragma unroll 4
            for (int kk = 0; kk < FF / 32; ++kk) {
                int kb = kk * 32 + q * 8;
                float4 x0 = *(const float4*)(xrow + kb);
                float4 x1 = *(const float4*)(xrow + kb + 4);
                half8 a;
                a[0] = (_Float16)x0.x; a[1] = (_Float16)x0.y;
                a[2] = (_Float16)x0.z; a[3] = (_Float16)x0.w;
                a[4] = (_Float16)x1.x; a[5] = (_Float16)x1.y;
                a[6] = (_Float16)x1.z; a[7] = (_Float16)x1.w;
                half8 b = *(const half8*)&wxh_l[r * KPF + kb];
                acc = __builtin_amdgcn_mfma_f32_16x16x32_f16(a, b, acc, 0, 0, 0);
            }
        }

        // GEMM2: h_{t-1} @ Whh_slice (K=1024). Issue ALL 32 h-loads first so a
        // single LLC round trip covers the whole K-loop (1 wg/CU -> VGPRs free).
        const _Float16* hrow = hbuf + cur * (BB * HH) + (size_t)mrow * HH;
        half8 areg[32];
        #pragma unroll
        for (int i = 0; i < 32; ++i)
            areg[i] = *(const half8*)(hrow + i * 32 + q * 8);
        #pragma unroll
        for (int i = 0; i < 32; ++i) {
            half8 b = *(const half8*)&whh_l[r * KPH + i * 32 + q * 8];
            acc = __builtin_amdgcn_mfma_f32_16x16x32_f16(areg[i], b, acc, 0, 0, 0);
        }

        // C layout: col = r, row = q*4+reg (+16*wid)
        #pragma unroll
        for (int reg = 0; reg < 4; ++reg)
            gbuf[(wid * 16 + q * 4 + reg) * 17 + r] = acc[reg];
        __syncthreads();

        // cell update: thread (m,d); gate cols {d, 4+d, 8+d, 12+d} = {f,i,o,g}
        float f_ = gbuf[m * 17 + 0  + d] + bias_l[0  + d];
        float i_ = gbuf[m * 17 + 4  + d] + bias_l[4  + d];
        float o_ = gbuf[m * 17 + 8  + d] + bias_l[8  + d];
        float g_ = gbuf[m * 17 + 12 + d] + bias_l[12 + d];
        c_reg = sigm(f_ + 1.0f) * c_reg + sigm(i_) * tanh_fast(g_);
        float cn = (c_reg - bnmu) * bniss + bnoff;
        h_out = sigm(o_) * tanh_fast(cn);
        hbuf[(cur ^ 1) * (BB * HH) + m * HH + mycol] = (_Float16)h_out;

        // prefetch next step's params BEFORE the barrier (independent of h)
        if (t + 1 < TT) {
            if constexpr (MODE == 0)
                xpv = *(const half4*)(xp + (((size_t)(t + 1) * 256 + wg) * 16 + r) * 64 + wid * 16 + q * 4);
            bnmu  = pmean[(t + 1) * HH + mycol];
            bniss = scale[(t + 1) * HH + mycol] * rsqrtf(pvar[(t + 1) * HH + mycol] + 1e-5f);
            bnoff = offs [(t + 1) * HH + mycol];
        }

        if constexpr (MODE == 2) grid.sync();
        else fastbar(bar, 256 * (nbar++), tid);
        cur ^= 1;
    }

    // after the final barrier nobody reads hbuf -> safe to write fp32 output
    out[m * HH + mycol] = h_out;
}

extern "C" void kernel_launch(void* const* d_in, const int* in_sizes, int n_in,
                              void* d_out, int out_size, void* d_ws, size_t ws_size,
                              hipStream_t stream) {
    const float* x     = (const float*)d_in[0];
    const float* w_xh  = (const float*)d_in[1];
    const float* w_hh  = (const float*)d_in[2];
    const float* bias  = (const float*)d_in[3];
    const float* scale = (const float*)d_in[4];
    const float* offs  = (const float*)d_in[5];
    const float* pmean = (const float*)d_in[6];
    const float* pvar  = (const float*)d_in[7];
    float* out = (float*)d_out;

    const size_t XPB = (size_t)TT * NG * BB * 2;  // 256 MiB
    int* bar = (int*)d_ws;
    _Float16* xp = (_Float16*)((char*)d_ws + 4096);
    const int mode = (ws_size >= XPB + 4096) ? 0 : (ws_size >= 256 ? 1 : 2);

    if (mode <= 1) hipMemsetAsync(d_ws, 0, 256, stream);
    if (mode == 0) xproj<<<dim3(NG / 64, TT / 4), 256, 0, stream>>>(x, w_xh, xp);

    const size_t shmem = (mode == 0) ? (33024 + 64 + 4352)
                                     : (33024 + 64 + 4352 + 16640);
    void* args[] = {&x, &w_xh, &w_hh, &bias, &scale, &offs, &pmean, &pvar,
                    &xp, &bar, &out};
    const void* f = (mode == 0) ? (const void*)&lstm_rec<0>
                  : (mode == 1) ? (const void*)&lstm_rec<1>
                                : (const void*)&lstm_rec<2>;
    hipLaunchCooperativeKernel(f, dim3(256), dim3(256), args, (uint32_t)shmem, stream);
}

// Round 4
// 6398.373 us; speedup vs baseline: 3.3054x; 2.1444x over previous
//
#include <hip/hip_runtime.h>
#include <hip/hip_cooperative_groups.h>
#include <math.h>

namespace cg = cooperative_groups;

#define BB 64
#define TT 512
#define FF 512
#define HH 1024
#define NG 4096  // 4H

typedef _Float16 half8 __attribute__((ext_vector_type(8)));
typedef float f32x4 __attribute__((ext_vector_type(4)));

__device__ __forceinline__ float sigm(float x) { return 1.0f / (1.0f + __expf(-x)); }
__device__ __forceinline__ float tanh_fast(float x) {
    x = fminf(fmaxf(x, -30.0f), 30.0f);
    float e = __expf(2.0f * x);
    return (e - 1.0f) / (e + 1.0f);
}

// ---------------------------------------------------------------------------
// x fp32 -> f16, same [B,T,F] layout. 32 MiB output into ws.
// ---------------------------------------------------------------------------
__global__ __launch_bounds__(256) void cvt_x(const float* __restrict__ x,
                                             _Float16* __restrict__ x16)
{
    size_t i = ((size_t)blockIdx.x * 256 + threadIdx.x) * 8;  // grid sized to cover B*T*F
    float4 a = *(const float4*)(x + i);
    float4 b = *(const float4*)(x + i + 4);
    half8 v;
    v[0] = (_Float16)a.x; v[1] = (_Float16)a.y; v[2] = (_Float16)a.z; v[3] = (_Float16)a.w;
    v[4] = (_Float16)b.x; v[5] = (_Float16)b.y; v[6] = (_Float16)b.z; v[7] = (_Float16)b.w;
    *(half8*)(x16 + i) = v;
}

// ---------------------------------------------------------------------------
// Flag-array grid barrier: NO shared-line RMWs.
//  arrive: per-wg release store to its own flag word (256 parallel stores).
//  wait:   wg0 wave0 gathers all 256 flags (4 coalesced loads/lane),
//          lane0 publishes epoch; everyone else polls epoch (read-only).
// caller must __syncthreads() before arrive (drains h stores to L2).
// ---------------------------------------------------------------------------
__device__ __forceinline__ void bar_arrive(int* flags, int ep, int wg, int tid) {
    if (tid == 0) {
        __builtin_amdgcn_fence(__ATOMIC_RELEASE, "agent");  // L2 -> LLC
        __hip_atomic_store(&flags[wg], ep, __ATOMIC_RELAXED, __HIP_MEMORY_SCOPE_AGENT);
    }
}
__device__ __forceinline__ void bar_wait(int* flags, int* epoch, int ep, int wg, int tid) {
    if (wg == 0 && tid < 64) {
        for (;;) {
            int ok = 1;
            #pragma unroll
            for (int j = 0; j < 4; ++j) {
                int v = __hip_atomic_load(&flags[tid + 64 * j], __ATOMIC_RELAXED,
                                          __HIP_MEMORY_SCOPE_AGENT);
                ok &= (v >= ep);
            }
            if (__all(ok)) break;
            __builtin_amdgcn_s_sleep(1);
        }
        if (tid == 0)
            __hip_atomic_store(epoch, ep, __ATOMIC_RELEASE, __HIP_MEMORY_SCOPE_AGENT);
    } else if (tid == 0) {
        while (__hip_atomic_load(epoch, __ATOMIC_RELAXED, __HIP_MEMORY_SCOPE_AGENT) < ep)
            __builtin_amdgcn_s_sleep(1);
    }
    if (tid == 0)
        __builtin_amdgcn_fence(__ATOMIC_ACQUIRE, "agent");  // inv L1/L2
    __syncthreads();
}

// ---------------------------------------------------------------------------
// Persistent recurrence. 256 wgs (1/CU) x 256 threads.
// MODE 0: x16 in ws + flag barrier.    MODE 1: fp32 x + flag barrier.
// MODE 2: fp32 x + cg::grid.sync (tiny-ws safety net).
// h double-buffer lives in d_out (2 * 64*1024 f16 == out_size*4 bytes).
// ---------------------------------------------------------------------------
template<int MODE>
__global__ __launch_bounds__(256, 1) void lstm_rec(
    const float* __restrict__ x, const float* __restrict__ w_xh,
    const float* __restrict__ w_hh, const float* __restrict__ bias,
    const float* __restrict__ scale, const float* __restrict__ offs,
    const float* __restrict__ pmean, const float* __restrict__ pvar,
    const _Float16* __restrict__ x16, int* flags, int* epoch,
    float* __restrict__ out)
{
    constexpr int KPH = HH + 8;   // f16 row stride 2064 B (16-B aligned)
    constexpr int KPF = FF + 8;   // 1040 B
    __shared__ __align__(16) _Float16 whh_l[16 * KPH];  // 33.0 KB
    __shared__ __align__(16) _Float16 wxh_l[16 * KPF];  // 16.6 KB
    __shared__ float bias_l[16];
    __shared__ float gbuf[64 * 17];

    const int wg  = blockIdx.x;
    const int tid = threadIdx.x;

    // one-time: gather this wg's 16 gemm columns of W_HH / W_XH into LDS (f16)
    for (int idx = tid; idx < 16 * HH; idx += 256) {
        int n = idx & 15, k = idx >> 4;
        int col = (n >> 2) * HH + wg * 4 + (n & 3);
        whh_l[n * KPH + k] = (_Float16)w_hh[k * NG + col];
    }
    for (int idx = tid; idx < 16 * FF; idx += 256) {
        int n = idx & 15, k = idx >> 4;
        int col = (n >> 2) * HH + wg * 4 + (n & 3);
        wxh_l[n * KPF + k] = (_Float16)w_xh[k * NG + col];
    }
    if (tid < 16) bias_l[tid] = bias[(tid >> 2) * HH + wg * 4 + (tid & 3)];

    _Float16* hbuf = (_Float16*)out;      // buf0=[0,64K) buf1=[64K,128K) f16 halves
    const int m = tid >> 2, d = tid & 3;  // epilogue ownership: (batch m, col d)
    const int mycol = wg * 4 + d;
    hbuf[m * HH + mycol] = (_Float16)0.0f;

    const int lane = tid & 63, wid = tid >> 6;
    const int q = lane >> 4, r = lane & 15;
    const int mrow = wid * 16 + r;        // A-frag row (batch)

    cg::grid_group grid = cg::this_grid();

    // prefetch step-0 BN params
    float bnmu  = pmean[mycol];
    float bniss = scale[mycol] * rsqrtf(pvar[mycol] + 1e-5f);
    float bnoff = offs[mycol];

    int ep = 1;
    __syncthreads();
    if constexpr (MODE == 2) grid.sync();
    else bar_arrive(flags, ep, wg, tid);

    // x-GEMM for t=0 (independent of h) — overlaps with barrier propagation
    auto xgemm = [&](int t) -> f32x4 {
        f32x4 a4 = {0.0f, 0.0f, 0.0f, 0.0f};
        if constexpr (MODE == 0) {
            const _Float16* xr = x16 + ((size_t)mrow * TT + t) * FF;
            #pragma unroll 4
            for (int kk = 0; kk < FF / 32; ++kk) {
                half8 a = *(const half8*)(xr + kk * 32 + q * 8);
                half8 b = *(const half8*)&wxh_l[r * KPF + kk * 32 + q * 8];
                a4 = __builtin_amdgcn_mfma_f32_16x16x32_f16(a, b, a4, 0, 0, 0);
            }
        } else {
            const float* xr = x + ((size_t)mrow * TT + t) * FF;
            #pragma unroll 4
            for (int kk = 0; kk < FF / 32; ++kk) {
                int kb = kk * 32 + q * 8;
                float4 x0 = *(const float4*)(xr + kb);
                float4 x1 = *(const float4*)(xr + kb + 4);
                half8 a;
                a[0] = (_Float16)x0.x; a[1] = (_Float16)x0.y;
                a[2] = (_Float16)x0.z; a[3] = (_Float16)x0.w;
                a[4] = (_Float16)x1.x; a[5] = (_Float16)x1.y;
                a[6] = (_Float16)x1.z; a[7] = (_Float16)x1.w;
                half8 b = *(const half8*)&wxh_l[r * KPF + kb];
                a4 = __builtin_amdgcn_mfma_f32_16x16x32_f16(a, b, a4, 0, 0, 0);
            }
        }
        return a4;
    };

    f32x4 xacc = xgemm(0);
    if constexpr (MODE != 2) bar_wait(flags, epoch, ep, wg, tid);
    ++ep;

    float c_reg = 0.0f, h_out = 0.0f;
    int cur = 0;

    for (int t = 0; t < TT; ++t) {
        f32x4 acc = xacc;

        // h-GEMM: h_{t-1} @ Whh_slice (K=1024), h f16 from L2/LLC
        const _Float16* hrow = hbuf + cur * (BB * HH) + (size_t)mrow * HH;
        #pragma unroll
        for (int i = 0; i < 32; ++i) {
            half8 a = *(const half8*)(hrow + i * 32 + q * 8);
            half8 b = *(const half8*)&whh_l[r * KPH + i * 32 + q * 8];
            acc = __builtin_amdgcn_mfma_f32_16x16x32_f16(a, b, acc, 0, 0, 0);
        }

        // C layout: col = r, row = q*4+reg (+16*wid)
        #pragma unroll
        for (int reg = 0; reg < 4; ++reg)
            gbuf[(wid * 16 + q * 4 + reg) * 17 + r] = acc[reg];
        __syncthreads();

        // cell update: thread (m,d); gate cols {d, 4+d, 8+d, 12+d} = {f,i,o,g}
        float f_ = gbuf[m * 17 + 0  + d] + bias_l[0  + d];
        float i_ = gbuf[m * 17 + 4  + d] + bias_l[4  + d];
        float o_ = gbuf[m * 17 + 8  + d] + bias_l[8  + d];
        float g_ = gbuf[m * 17 + 12 + d] + bias_l[12 + d];
        c_reg = sigm(f_ + 1.0f) * c_reg + sigm(i_) * tanh_fast(g_);
        float cn = (c_reg - bnmu) * bniss + bnoff;
        h_out = sigm(o_) * tanh_fast(cn);
        hbuf[(cur ^ 1) * (BB * HH) + m * HH + mycol] = (_Float16)h_out;

        // prefetch next BN params (independent of h)
        if (t + 1 < TT) {
            bnmu  = pmean[(t + 1) * HH + mycol];
            bniss = scale[(t + 1) * HH + mycol] * rsqrtf(pvar[(t + 1) * HH + mycol] + 1e-5f);
            bnoff = offs [(t + 1) * HH + mycol];
        }

        __syncthreads();  // drains h stores to L2; gbuf reads done
        if constexpr (MODE == 2) {
            if (t + 1 < TT) xacc = xgemm(t + 1);
            grid.sync();
        } else {
            bar_arrive(flags, ep, wg, tid);
            if (t + 1 < TT) xacc = xgemm(t + 1);   // hidden under barrier wait
            bar_wait(flags, epoch, ep, wg, tid);
        }
        ++ep;
        cur ^= 1;
    }

    // after the final barrier nobody reads hbuf -> safe to write fp32 output
    out[m * HH + mycol] = h_out;
}

extern "C" void kernel_launch(void* const* d_in, const int* in_sizes, int n_in,
                              void* d_out, int out_size, void* d_ws, size_t ws_size,
                              hipStream_t stream) {
    const float* x     = (const float*)d_in[0];
    const float* w_xh  = (const float*)d_in[1];
    const float* w_hh  = (const float*)d_in[2];
    const float* bias  = (const float*)d_in[3];
    const float* scale = (const float*)d_in[4];
    const float* offs  = (const float*)d_in[5];
    const float* pmean = (const float*)d_in[6];
    const float* pvar  = (const float*)d_in[7];
    float* out = (float*)d_out;

    int* flags = (int*)d_ws;                         // 1 KB
    int* epoch = (int*)((char*)d_ws + 1024);
    _Float16* x16 = (_Float16*)((char*)d_ws + 4096); // 32 MiB
    const size_t X16B = (size_t)BB * TT * FF * 2;
    const int mode = (ws_size >= X16B + 4096) ? 0 : (ws_size >= 2048 ? 1 : 2);

    if (mode <= 1) (void)hipMemsetAsync(d_ws, 0, 2048, stream);
    if (mode == 0) {
        const size_t nelem = (size_t)BB * TT * FF;
        cvt_x<<<dim3((unsigned)(nelem / (256 * 8))), 256, 0, stream>>>(x, x16);
    }

    void* args[] = {&x, &w_xh, &w_hh, &bias, &scale, &offs, &pmean, &pvar,
                    &x16, &flags, &epoch, &out};
    const void* f = (mode == 0) ? (const void*)&lstm_rec<0>
                  : (mode == 1) ? (const void*)&lstm_rec<1>
                                : (const void*)&lstm_rec<2>;
    (void)hipLaunchCooperativeKernel(f, dim3(256), dim3(256), args, 0, stream);
}

// Round 5
// 5172.629 us; speedup vs baseline: 4.0886x; 1.2370x over previous
//
#include <hip/hip_runtime.h>
#include <hip/hip_cooperative_groups.h>
#include <math.h>

namespace cg = cooperative_groups;

#define BB 64
#define TT 512
#define FF 512
#define HH 1024
#define NG 4096  // 4H

typedef _Float16 half8 __attribute__((ext_vector_type(8)));
typedef float f32x4 __attribute__((ext_vector_type(4)));

__device__ __forceinline__ float sigm(float x) { return 1.0f / (1.0f + __expf(-x)); }
__device__ __forceinline__ float tanh_fast(float x) {
    x = fminf(fmaxf(x, -30.0f), 30.0f);
    float e = __expf(2.0f * x);
    return (e - 1.0f) / (e + 1.0f);
}

// ---------------------------------------------------------------------------
// x fp32 -> f16, same [B,T,F] layout. 32 MiB output into ws.
// ---------------------------------------------------------------------------
__global__ __launch_bounds__(256) void cvt_x(const float* __restrict__ x,
                                             _Float16* __restrict__ x16)
{
    size_t i = ((size_t)blockIdx.x * 256 + threadIdx.x) * 8;
    float4 a = *(const float4*)(x + i);
    float4 b = *(const float4*)(x + i + 4);
    half8 v;
    v[0] = (_Float16)a.x; v[1] = (_Float16)a.y; v[2] = (_Float16)a.z; v[3] = (_Float16)a.w;
    v[4] = (_Float16)b.x; v[5] = (_Float16)b.y; v[6] = (_Float16)b.z; v[7] = (_Float16)b.w;
    *(half8*)(x16 + i) = v;
}

// ---------------------------------------------------------------------------
// Flag-array grid barrier, fence-light version.
// Precondition: ALL cross-wg-visible data (h) is written with agent-scope
// write-through atomic stores, so there are never dirty L2 lines to flush.
//  arrive: s_waitcnt vmcnt(0) (h stores at LLC) + relaxed flag store. NO wbl2.
//  wait:   wg0 wave0 gathers 256 flags, publishes epoch; others poll epoch.
//          Then a plain acquire fence (buffer_inv tag-invalidate, no data
//          movement since nothing is dirty) + __syncthreads.
// ---------------------------------------------------------------------------
__device__ __forceinline__ void bar_arrive(int* flags, int ep, int wg, int tid) {
    if (tid == 0) {
        __builtin_amdgcn_s_waitcnt(0xF70);  // vmcnt(0) only (exp=7, lgkm=15)
        __hip_atomic_store(&flags[wg], ep, __ATOMIC_RELAXED, __HIP_MEMORY_SCOPE_AGENT);
    }
}
__device__ __forceinline__ void bar_wait(int* flags, int* epoch, int ep, int wg, int tid) {
    if (wg == 0 && tid < 64) {
        for (;;) {
            int ok = 1;
            #pragma unroll
            for (int j = 0; j < 4; ++j) {
                int v = __hip_atomic_load(&flags[tid + 64 * j], __ATOMIC_RELAXED,
                                          __HIP_MEMORY_SCOPE_AGENT);
                ok &= (v >= ep);
            }
            if (__all(ok)) break;
            __builtin_amdgcn_s_sleep(1);
        }
        if (tid == 0)
            __hip_atomic_store(epoch, ep, __ATOMIC_RELAXED, __HIP_MEMORY_SCOPE_AGENT);
    } else if (tid == 0) {
        while (__hip_atomic_load(epoch, __ATOMIC_RELAXED, __HIP_MEMORY_SCOPE_AGENT) < ep)
            __builtin_amdgcn_s_sleep(1);
    }
    if (tid == 0)
        __builtin_amdgcn_fence(__ATOMIC_ACQUIRE, "agent");  // buffer_inv (tag-only)
    __syncthreads();
}

// ---------------------------------------------------------------------------
// Persistent recurrence. 256 wgs (1/CU) x 256 threads.
// MODE 0: x16 in ws + flag barrier.    MODE 1: fp32 x + flag barrier.
// MODE 2: fp32 x + cg::grid.sync (tiny-ws safety net).
// h double-buffer lives in d_out (2 * 64*1024 f16 == out_size*4 bytes).
// h writes are agent-scope atomic (write-through) — see barrier comment.
// ---------------------------------------------------------------------------
template<int MODE>
__global__ __launch_bounds__(256, 1) void lstm_rec(
    const float* __restrict__ x, const float* __restrict__ w_xh,
    const float* __restrict__ w_hh, const float* __restrict__ bias,
    const float* __restrict__ scale, const float* __restrict__ offs,
    const float* __restrict__ pmean, const float* __restrict__ pvar,
    const _Float16* __restrict__ x16, int* flags, int* epoch,
    float* __restrict__ out)
{
    constexpr int KPH = HH + 8;   // f16 row stride 2064 B (16-B aligned)
    constexpr int KPF = FF + 8;   // 1040 B
    __shared__ __align__(16) _Float16 whh_l[16 * KPH];  // 33.0 KB
    __shared__ __align__(16) _Float16 wxh_l[16 * KPF];  // 16.6 KB
    __shared__ float bias_l[16];
    __shared__ float gbuf[64 * 17];

    const int wg  = blockIdx.x;
    const int tid = threadIdx.x;

    // one-time: gather this wg's 16 gemm columns of W_HH / W_XH into LDS (f16)
    for (int idx = tid; idx < 16 * HH; idx += 256) {
        int n = idx & 15, k = idx >> 4;
        int col = (n >> 2) * HH + wg * 4 + (n & 3);
        whh_l[n * KPH + k] = (_Float16)w_hh[k * NG + col];
    }
    for (int idx = tid; idx < 16 * FF; idx += 256) {
        int n = idx & 15, k = idx >> 4;
        int col = (n >> 2) * HH + wg * 4 + (n & 3);
        wxh_l[n * KPF + k] = (_Float16)w_xh[k * NG + col];
    }
    if (tid < 16) bias_l[tid] = bias[(tid >> 2) * HH + wg * 4 + (tid & 3)];

    _Float16* hbuf = (_Float16*)out;      // buf0=[0,64K) buf1=[64K,128K) f16 halves
    const int m = tid >> 2, d = tid & 3;  // epilogue ownership: (batch m, col d)
    const int mycol = wg * 4 + d;
    // zero h buffer 0 — write-through so it's at LLC before the first barrier
    if ((d & 1) == 0)
        __hip_atomic_store((unsigned*)(hbuf + m * HH + mycol), 0u,
                           __ATOMIC_RELAXED, __HIP_MEMORY_SCOPE_AGENT);

    const int lane = tid & 63, wid = tid >> 6;
    const int q = lane >> 4, r = lane & 15;
    const int mrow = wid * 16 + r;        // A-frag row (batch)

    cg::grid_group grid = cg::this_grid();

    // prefetch step-0 BN params
    float bnmu  = pmean[mycol];
    float bniss = scale[mycol] * rsqrtf(pvar[mycol] + 1e-5f);
    float bnoff = offs[mycol];

    int ep = 1;
    __syncthreads();
    if constexpr (MODE == 2) grid.sync();
    else bar_arrive(flags, ep, wg, tid);

    // x-GEMM for t (independent of h) — overlaps with barrier propagation
    auto xgemm = [&](int t) -> f32x4 {
        f32x4 a4 = {0.0f, 0.0f, 0.0f, 0.0f};
        if constexpr (MODE == 0) {
            const _Float16* xr = x16 + ((size_t)mrow * TT + t) * FF;
            #pragma unroll 4
            for (int kk = 0; kk < FF / 32; ++kk) {
                half8 a = *(const half8*)(xr + kk * 32 + q * 8);
                half8 b = *(const half8*)&wxh_l[r * KPF + kk * 32 + q * 8];
                a4 = __builtin_amdgcn_mfma_f32_16x16x32_f16(a, b, a4, 0, 0, 0);
            }
        } else {
            const float* xr = x + ((size_t)mrow * TT + t) * FF;
            #pragma unroll 4
            for (int kk = 0; kk < FF / 32; ++kk) {
                int kb = kk * 32 + q * 8;
                float4 x0 = *(const float4*)(xr + kb);
                float4 x1 = *(const float4*)(xr + kb + 4);
                half8 a;
                a[0] = (_Float16)x0.x; a[1] = (_Float16)x0.y;
                a[2] = (_Float16)x0.z; a[3] = (_Float16)x0.w;
                a[4] = (_Float16)x1.x; a[5] = (_Float16)x1.y;
                a[6] = (_Float16)x1.z; a[7] = (_Float16)x1.w;
                half8 b = *(const half8*)&wxh_l[r * KPF + kb];
                a4 = __builtin_amdgcn_mfma_f32_16x16x32_f16(a, b, a4, 0, 0, 0);
            }
        }
        return a4;
    };

    f32x4 xacc = xgemm(0);
    if constexpr (MODE != 2) bar_wait(flags, epoch, ep, wg, tid);
    ++ep;

    float c_reg = 0.0f, h_out = 0.0f;
    int cur = 0;

    for (int t = 0; t < TT; ++t) {
        f32x4 acc = xacc;

        // h-GEMM: h_{t-1} @ Whh_slice (K=1024), h f16 from L2 (refilled from LLC)
        const _Float16* hrow = hbuf + cur * (BB * HH) + (size_t)mrow * HH;
        #pragma unroll
        for (int i = 0; i < 32; ++i) {
            half8 a = *(const half8*)(hrow + i * 32 + q * 8);
            half8 b = *(const half8*)&whh_l[r * KPH + i * 32 + q * 8];
            acc = __builtin_amdgcn_mfma_f32_16x16x32_f16(a, b, acc, 0, 0, 0);
        }

        // C layout: col = r, row = q*4+reg (+16*wid)
        #pragma unroll
        for (int reg = 0; reg < 4; ++reg)
            gbuf[(wid * 16 + q * 4 + reg) * 17 + r] = acc[reg];
        __syncthreads();

        // cell update: thread (m,d); gate cols {d, 4+d, 8+d, 12+d} = {f,i,o,g}
        float f_ = gbuf[m * 17 + 0  + d] + bias_l[0  + d];
        float i_ = gbuf[m * 17 + 4  + d] + bias_l[4  + d];
        float o_ = gbuf[m * 17 + 8  + d] + bias_l[8  + d];
        float g_ = gbuf[m * 17 + 12 + d] + bias_l[12 + d];
        c_reg = sigm(f_ + 1.0f) * c_reg + sigm(i_) * tanh_fast(g_);
        float cn = (c_reg - bnmu) * bniss + bnoff;
        h_out = sigm(o_) * tanh_fast(cn);

        // pack 2 f16 across the d-pair and write-through to LLC (4-B atomic)
        {
            _Float16 hv = (_Float16)h_out;
            unsigned short hb = __builtin_bit_cast(unsigned short, hv);
            unsigned short pb = (unsigned short)__shfl_xor((int)hb, 1, 64);
            if ((d & 1) == 0) {
                unsigned packed = (unsigned)hb | ((unsigned)pb << 16);
                __hip_atomic_store(
                    (unsigned*)(hbuf + (cur ^ 1) * (BB * HH) + m * HH + mycol),
                    packed, __ATOMIC_RELAXED, __HIP_MEMORY_SCOPE_AGENT);
            }
        }

        // prefetch next BN params (independent of h)
        if (t + 1 < TT) {
            bnmu  = pmean[(t + 1) * HH + mycol];
            bniss = scale[(t + 1) * HH + mycol] * rsqrtf(pvar[(t + 1) * HH + mycol] + 1e-5f);
            bnoff = offs [(t + 1) * HH + mycol];
        }

        __syncthreads();  // all waves drain vmcnt (h stores reach LLC); gbuf done
        if constexpr (MODE == 2) {
            if (t + 1 < TT) xacc = xgemm(t + 1);
            grid.sync();
        } else {
            bar_arrive(flags, ep, wg, tid);
            if (t + 1 < TT) xacc = xgemm(t + 1);   // hidden under barrier wait
            bar_wait(flags, epoch, ep, wg, tid);
        }
        ++ep;
        cur ^= 1;
    }

    // after the final barrier nobody reads hbuf -> safe to write fp32 output
    out[m * HH + mycol] = h_out;
}

extern "C" void kernel_launch(void* const* d_in, const int* in_sizes, int n_in,
                              void* d_out, int out_size, void* d_ws, size_t ws_size,
                              hipStream_t stream) {
    const float* x     = (const float*)d_in[0];
    const float* w_xh  = (const float*)d_in[1];
    const float* w_hh  = (const float*)d_in[2];
    const float* bias  = (const float*)d_in[3];
    const float* scale = (const float*)d_in[4];
    const float* offs  = (const float*)d_in[5];
    const float* pmean = (const float*)d_in[6];
    const float* pvar  = (const float*)d_in[7];
    float* out = (float*)d_out;

    int* flags = (int*)d_ws;                         // 1 KB
    int* epoch = (int*)((char*)d_ws + 1024);
    _Float16* x16 = (_Float16*)((char*)d_ws + 4096); // 32 MiB
    const size_t X16B = (size_t)BB * TT * FF * 2;
    const int mode = (ws_size >= X16B + 4096) ? 0 : (ws_size >= 2048 ? 1 : 2);

    if (mode <= 1) (void)hipMemsetAsync(d_ws, 0, 2048, stream);
    if (mode == 0) {
        const size_t nelem = (size_t)BB * TT * FF;
        cvt_x<<<dim3((unsigned)(nelem / (256 * 8))), 256, 0, stream>>>(x, x16);
    }

    void* args[] = {&x, &w_xh, &w_hh, &bias, &scale, &offs, &pmean, &pvar,
                    &x16, &flags, &epoch, &out};
    const void* f = (mode == 0) ? (const void*)&lstm_rec<0>
                  : (mode == 1) ? (const void*)&lstm_rec<1>
                                : (const void*)&lstm_rec<2>;
    (void)hipLaunchCooperativeKernel(f, dim3(256), dim3(256), args, 0, stream);
}